// Round 16
// baseline (233.260 us; speedup 1.0000x reference)
//
#include <hip/hip_runtime.h>
#include <math.h>
#include <stdint.h>

#define B_  64
#define E_  32
#define L_  512
#define D_  768
#define C_  1024
#define H_  8
#define EG_ 32768
#define SH_ 512
#define N_  2048   // B*E
#define ND_ (N_ * D_)

typedef __bf16 bf16x8 __attribute__((ext_vector_type(8)));
typedef float f32x4 __attribute__((ext_vector_type(4)));
typedef unsigned short u16;
typedef u16 u16x4 __attribute__((ext_vector_type(4)));

// ---------------------------------------------------------------- helpers

__device__ __forceinline__ u16 bf16_rn(float x) {
  unsigned u = __builtin_bit_cast(unsigned, x);
  unsigned r = u + 0x7FFFu + ((u >> 16) & 1u);
  return (u16)(r >> 16);
}

__device__ __forceinline__ float bf2f(u16 u) {
  return __builtin_bit_cast(float, (unsigned)u << 16);
}

__device__ __forceinline__ void gload16(const void* g, void* l) {
  __builtin_amdgcn_global_load_lds(
      (const __attribute__((address_space(1))) void*)(unsigned long long)(uintptr_t)g,
      (__attribute__((address_space(3))) void*)(unsigned int)(uintptr_t)l,
      16, 0, 0);
}

// XCD-aware chunked swizzle (grid must be divisible by 8)
__device__ __forceinline__ int xcd_swz(int bid, int grid) {
  return (bid & 7) * (grid >> 3) + (bid >> 3);
}

// ------------------------------------------------- merged weight prep (9 mats)
__global__ void k_wt9(const float* __restrict__ s0, const float* __restrict__ s1,
                      const float* __restrict__ s2, const float* __restrict__ s3,
                      const float* __restrict__ s4, const float* __restrict__ s5,
                      const float* __restrict__ s6, const float* __restrict__ s7,
                      const float* __restrict__ s8, u16* __restrict__ dstBase) {
  int x = blockIdx.x;
  const float* W; u16* TH; int K, Nc;
  if (x < 384) {                       // W1: 768x512
    W = s0; TH = dstBase; K = D_; Nc = SH_;
  } else if (x < 384 + 4 * 768) {      // conv1 q/k/v/s: 768x1024
    int i = (x - 384) / 768; x = (x - 384) % 768;
    W = (i == 0) ? s1 : (i == 1) ? s2 : (i == 2) ? s3 : s4;
    TH = dstBase + SH_ * D_ + (size_t)i * C_ * D_; K = D_; Nc = C_;
  } else {                             // conv2 q/k/v/s: 1024x1024
    int i = (x - 3456) / 1024; x = (x - 3456) % 1024;
    W = (i == 0) ? s5 : (i == 1) ? s6 : (i == 2) ? s7 : s8;
    TH = dstBase + SH_ * D_ + 4 * (size_t)C_ * D_ + (size_t)i * C_ * C_; K = C_; Nc = C_;
  }
  __shared__ float Ts[32][33];
  int nbk = K >> 5;
  int bk = x % nbk, bn = x / nbk;
  int tid = threadIdx.x;
  int tx = tid & 31, ty = tid >> 5;
  for (int r = ty; r < 32; r += 8)
    Ts[r][tx] = W[(size_t)(bk * 32 + r) * Nc + bn * 32 + tx];
  __syncthreads();
  for (int r = ty; r < 32; r += 8) {
    float v = Ts[tx][r];
    TH[(size_t)(bn * 32 + r) * K + bk * 32 + tx] = bf16_rn(v);
  }
}

// ------------------------------------------------- MFMA GEMM core, BK=64
// (used by k_gemm4_m) 128x128 tile, 4 waves.
__device__ __forceinline__ void gemm_core(
    const float* __restrict__ X, const u16* __restrict__ Bt,
    int K, int row0, int col0,
    u16* Ah, u16* Bh, f32x4 acc[4][4])
{
  int tid = threadIdx.x;
  int lane = tid & 63, w = tid >> 6;

  int aoff[4], boff[4];
#pragma unroll
  for (int i = 0; i < 4; i++) {
    int kc = lane >> 4;
    int rT = (w & 1) * 64 + i * 16 + (lane & 15);
    aoff[i] = rT * 128 + (((kc ^ (rT & 7)) & 7) << 4);
    int cT = (w >> 1) * 64 + i * 16 + (lane & 15);
    boff[i] = cT * 128 + (((kc ^ (cT & 7)) & 7) << 4);
  }

  int nkt = K >> 6;
  for (int kt = 0; kt < nkt; kt++) {
    int k0 = kt << 6;
    if (kt) __syncthreads();
#pragma unroll
    for (int p = 0; p < 8; p++) {
      int idx = tid + p * 256;           // 0..2047
      int r = idx >> 4, c4 = idx & 15;
      float4 v = *(const float4*)&X[(size_t)(row0 + r) * K + k0 + c4 * 4];
      u16x4 hv = {bf16_rn(v.x), bf16_rn(v.y), bf16_rn(v.z), bf16_rn(v.w)};
      int off = r * 128 + ((((c4 >> 1) ^ (r & 7)) & 7) << 4) + (c4 & 1) * 8;
      *(u16x4*)((char*)Ah + off) = hv;
    }
#pragma unroll
    for (int q = 0; q < 4; q++) {
      int rT = w * 32 + q * 8 + (lane >> 3);
      int cs = (lane & 7) ^ (rT & 7);
      size_t gb = (size_t)(col0 + rT) * K + k0 + cs * 8;
      int lb = (w * 32 + q * 8) * 64;
      gload16(&Bt[gb], &Bh[lb]);
    }
    __syncthreads();
    bf16x8 ah0[4], ah1[4];
#pragma unroll
    for (int i = 0; i < 4; i++) {
      ah0[i] = *(const bf16x8*)((const char*)Ah + aoff[i]);
      ah1[i] = *(const bf16x8*)((const char*)Ah + (aoff[i] ^ 64));
    }
#pragma unroll
    for (int j = 0; j < 4; j++) {
      bf16x8 bh0 = *(const bf16x8*)((const char*)Bh + boff[j]);
#pragma unroll
      for (int i = 0; i < 4; i++)
        acc[i][j] = __builtin_amdgcn_mfma_f32_16x16x32_bf16(ah0[i], bh0, acc[i][j], 0, 0, 0);
      bf16x8 bh1 = *(const bf16x8*)((const char*)Bh + (boff[j] ^ 64));
#pragma unroll
      for (int i = 0; i < 4; i++)
        acc[i][j] = __builtin_amdgcn_mfma_f32_16x16x32_bf16(ah1[i], bh1, acc[i][j], 0, 0, 0);
    }
  }
}

// ------------------------------------------------- span MLP: 128x128 tile/block
// grid 1024 = rb(256) x cb(4), XCD-chunk-swizzled (cb-siblings share XCD L2).
// 512 threads, 8 waves: rh=w&1 (64 rows) x cq=w>>1 (32 cols). 4 blocks/CU.
// lh read once; writes per-colblock partials att4[cb][32768].
__global__ __launch_bounds__(512, 4) void k_span_m(
    const float* __restrict__ lh, const u16* __restrict__ W1t,
    const float* __restrict__ b1, const float* __restrict__ W2,
    float* __restrict__ att4) {
  __shared__ __align__(16) u16 Ah[128 * 64];   // 16 KB
  __shared__ __align__(16) u16 Bh[128 * 64];   // 16 KB
  int wid = xcd_swz(blockIdx.x, 1024);
  int rb = wid >> 2, cb = wid & 3;
  int row0 = rb * 128, col0 = cb * 128;
  int tid = threadIdx.x, lane = tid & 63, w = tid >> 6;
  int rh = w & 1, cq = w >> 1;

  f32x4 acc[4][2];
#pragma unroll
  for (int i = 0; i < 4; i++)
#pragma unroll
    for (int j = 0; j < 2; j++) acc[i][j] = (f32x4){0.f, 0.f, 0.f, 0.f};

  int kc = lane >> 4;
  int aoff[4], boff[2];
#pragma unroll
  for (int i = 0; i < 4; i++) {
    int rT = rh * 64 + i * 16 + (lane & 15);
    aoff[i] = rT * 128 + (((kc ^ (rT & 7)) & 7) << 4);
  }
#pragma unroll
  for (int j = 0; j < 2; j++) {
    int cT = cq * 32 + j * 16 + (lane & 15);
    boff[j] = cT * 128 + (((kc ^ (cT & 7)) & 7) << 4);
  }

  for (int kt = 0; kt < 12; kt++) {     // K = 768, BK = 64
    int k0 = kt << 6;
    if (kt) __syncthreads();
    // A: 128 rows x 64k from lh; 4 float4 / thread
#pragma unroll
    for (int p = 0; p < 4; p++) {
      int idx = tid + p * 512;           // 0..2047
      int r = idx >> 4, c4 = idx & 15;
      float4 v = *(const float4*)&lh[(size_t)(row0 + r) * D_ + k0 + c4 * 4];
      u16x4 hv = {bf16_rn(v.x), bf16_rn(v.y), bf16_rn(v.z), bf16_rn(v.w)};
      int off = r * 128 + ((((c4 >> 1) ^ (r & 7)) & 7) << 4) + (c4 & 1) * 8;
      *(u16x4*)((char*)Ah + off) = hv;
    }
    // B: 128 W1t rows x 64k via global_load_lds (inverse-swizzled source)
#pragma unroll
    for (int q = 0; q < 2; q++) {
      int rT = w * 16 + q * 8 + (lane >> 3);   // 0..127
      int cs = (lane & 7) ^ (rT & 7);
      size_t gb = (size_t)(col0 + rT) * D_ + k0 + cs * 8;
      int lb = (w * 16 + q * 8) * 64;          // u16 units, wave-uniform
      gload16(&W1t[gb], &Bh[lb]);
    }
    __syncthreads();
    bf16x8 ah0[4], ah1[4];
#pragma unroll
    for (int i = 0; i < 4; i++) {
      ah0[i] = *(const bf16x8*)((const char*)Ah + aoff[i]);
      ah1[i] = *(const bf16x8*)((const char*)Ah + (aoff[i] ^ 64));
    }
#pragma unroll
    for (int j = 0; j < 2; j++) {
      bf16x8 bh0 = *(const bf16x8*)((const char*)Bh + boff[j]);
#pragma unroll
      for (int i = 0; i < 4; i++)
        acc[i][j] = __builtin_amdgcn_mfma_f32_16x16x32_bf16(ah0[i], bh0, acc[i][j], 0, 0, 0);
      bf16x8 bh1 = *(const bf16x8*)((const char*)Bh + (boff[j] ^ 64));
#pragma unroll
      for (int i = 0; i < 4; i++)
        acc[i][j] = __builtin_amdgcn_mfma_f32_16x16x32_bf16(ah1[i], bh1, acc[i][j], 0, 0, 0);
    }
  }

  // epilogue: per-row partial over this block's 128 cols -> att4[cb]
  float b1v[2], w2v[2];
#pragma unroll
  for (int j = 0; j < 2; j++) {
    int col = col0 + cq * 32 + j * 16 + (lane & 15);
    b1v[j] = b1[col]; w2v[j] = W2[col];
  }
  __syncthreads();                       // done with Ah; reuse as reduce buffer
  float* sred = (float*)Ah;              // [4][128] = 2 KB
#pragma unroll
  for (int i = 0; i < 4; i++) {
#pragma unroll
    for (int r = 0; r < 4; r++) {
      float s = 0.f;
#pragma unroll
      for (int j = 0; j < 2; j++) {
        float h = acc[i][j][r] + b1v[j];
        s += fmaxf(h, 0.f) * w2v[j];
      }
      s += __shfl_xor(s, 1); s += __shfl_xor(s, 2);
      s += __shfl_xor(s, 4); s += __shfl_xor(s, 8);
      if ((lane & 15) == 0)
        sred[cq * 128 + rh * 64 + i * 16 + (lane >> 4) * 4 + r] = s;
    }
  }
  __syncthreads();
  if (tid < 128)
    att4[(size_t)cb * 32768 + row0 + tid] =
        sred[tid] + sred[128 + tid] + sred[256 + tid] + sred[384 + tid];
}

// ------------------------------------------------- probs: masked softmax -> bf16
__global__ void k_probs(const float* __restrict__ att4, const float* __restrict__ b2,
                        const float* __restrict__ mask, u16* __restrict__ pr) {
  int bi = blockIdx.x >> 2, eg = blockIdx.x & 3;
  int tid = threadIdx.x, lane = tid & 63, w = tid >> 6;
  __shared__ float att_s[512];
  float b2v = b2[0];
  int r0 = bi * 512 + tid;
  float s0 = b2v, s1 = b2v;
#pragma unroll
  for (int p = 0; p < 4; p++) {
    s0 += att4[(size_t)p * 32768 + r0];
    s1 += att4[(size_t)p * 32768 + r0 + 256];
  }
  att_s[tid] = s0;
  att_s[tid + 256] = s1;
  __syncthreads();
#pragma unroll
  for (int it = 0; it < 2; it++) {
    int e = eg * 8 + it * 4 + w;
    const float* mrow = &mask[(size_t)(bi * E_ + e) * L_];
    float4 m0 = *(const float4*)&mrow[lane * 8];
    float4 m1 = *(const float4*)&mrow[lane * 8 + 4];
    float4 a0 = *(const float4*)&att_s[lane * 8];
    float4 a1 = *(const float4*)&att_s[lane * 8 + 4];
    float v[8];
    v[0] = a0.x - 1e5f * (1.f - m0.x); v[1] = a0.y - 1e5f * (1.f - m0.y);
    v[2] = a0.z - 1e5f * (1.f - m0.z); v[3] = a0.w - 1e5f * (1.f - m0.w);
    v[4] = a1.x - 1e5f * (1.f - m1.x); v[5] = a1.y - 1e5f * (1.f - m1.y);
    v[6] = a1.z - 1e5f * (1.f - m1.z); v[7] = a1.w - 1e5f * (1.f - m1.w);
    float mx = v[0];
#pragma unroll
    for (int i = 1; i < 8; i++) mx = fmaxf(mx, v[i]);
#pragma unroll
    for (int o = 32; o; o >>= 1) mx = fmaxf(mx, __shfl_xor(mx, o));
    float s = 0.f;
#pragma unroll
    for (int i = 0; i < 8; i++) { v[i] = expf(v[i] - mx); s += v[i]; }
#pragma unroll
    for (int o = 32; o; o >>= 1) s += __shfl_xor(s, o);
    float inv = 1.f / s;
    u16x4 o0 = {bf16_rn(v[0] * inv), bf16_rn(v[1] * inv), bf16_rn(v[2] * inv), bf16_rn(v[3] * inv)};
    u16x4 o1 = {bf16_rn(v[4] * inv), bf16_rn(v[5] * inv), bf16_rn(v[6] * inv), bf16_rn(v[7] * inv)};
    u16* prow = &pr[(size_t)(bi * E_ + e) * L_];
    *(u16x4*)&prow[lane * 8] = o0;
    *(u16x4*)&prow[lane * 8 + 4] = o1;
  }
}

// ------------------------------------------------- pool via MFMA (bf16 probs)
__global__ __launch_bounds__(256) void k_pool_m(const float* __restrict__ lh,
    const u16* __restrict__ pr, float* __restrict__ node0) {
  __shared__ __align__(16) u16 As[32 * 32];
  __shared__ __align__(16) u16 Bs[32 * 128];
  int bi = blockIdx.x / 6, dc = blockIdx.x % 6;
  int col0 = dc * 128;
  int tid = threadIdx.x, lane = tid & 63, w = tid >> 6;
  const float* lhb = lh + (size_t)bi * L_ * D_;
  const u16* prb = pr + (size_t)bi * E_ * L_;

  f32x4 acc[2][2];
#pragma unroll
  for (int m = 0; m < 2; m++)
#pragma unroll
    for (int c = 0; c < 2; c++) acc[m][c] = (f32x4){0.f, 0.f, 0.f, 0.f};

  int aoff[2];
#pragma unroll
  for (int m = 0; m < 2; m++) {
    int kc = lane >> 4;
    int e = m * 16 + (lane & 15);
    aoff[m] = e * 64 + (((kc ^ ((e >> 1) & 3)) & 3) << 4);
  }
  int se = tid >> 3, sk4 = tid & 7;
  int saoff = se * 64 + ((((sk4 >> 1) ^ ((se >> 1) & 3)) & 3) << 4) + (sk4 & 1) * 8;

  for (int kt = 0; kt < 16; kt++) {
    int l0 = kt << 5;
    if (kt) __syncthreads();
    {
      u16x4 hv = *(const u16x4*)&prb[(size_t)se * L_ + l0 + sk4 * 4];
      *(u16x4*)((char*)As + saoff) = hv;
    }
#pragma unroll
    for (int p = 0; p < 4; p++) {
      int idx = tid + p * 256;
      int k = idx >> 5, c4 = idx & 31;
      float4 v = *(const float4*)&lhb[(size_t)(l0 + k) * D_ + col0 + c4 * 4];
      u16x4 hv = {bf16_rn(v.x), bf16_rn(v.y), bf16_rn(v.z), bf16_rn(v.w)};
      *(u16x4*)&Bs[k * 128 + c4 * 4] = hv;
    }
    __syncthreads();
    bf16x8 af[2];
#pragma unroll
    for (int m = 0; m < 2; m++)
      af[m] = *(const bf16x8*)((const char*)As + aoff[m]);
#pragma unroll
    for (int c = 0; c < 2; c++) {
      int colT = w * 32 + c * 16 + (lane & 15);
      int kg = (lane >> 4) * 8;
      union { bf16x8 v; u16 u[8]; } bb;
#pragma unroll
      for (int j = 0; j < 8; j++) bb.u[j] = Bs[(kg + j) * 128 + colT];
#pragma unroll
      for (int m = 0; m < 2; m++)
        acc[m][c] = __builtin_amdgcn_mfma_f32_16x16x32_bf16(af[m], bb.v, acc[m][c], 0, 0, 0);
    }
  }
#pragma unroll
  for (int m = 0; m < 2; m++)
#pragma unroll
    for (int c = 0; c < 2; c++) {
      int col = col0 + w * 32 + c * 16 + (lane & 15);
#pragma unroll
      for (int r = 0; r < 4; r++) {
        int e = m * 16 + (lane >> 4) * 4 + r;
        node0[(size_t)(bi * E_ + e) * D_ + col] = acc[m][c][r];
      }
    }
}

// ------------------------------------------------- fused q/k/v/skip GEMM (MFMA)
// q,k,v outputs bf16; skip output fp32. XCD-chunk-swizzled.
__global__ __launch_bounds__(256) void k_gemm4_m(
    const float* __restrict__ X, int K,
    const u16* __restrict__ Wt,
    const float* __restrict__ bb0, const float* __restrict__ bb1,
    const float* __restrict__ bb2, const float* __restrict__ bb3,
    u16* __restrict__ O0, u16* __restrict__ O1,
    u16* __restrict__ O2, float* __restrict__ O3) {
  __shared__ __align__(16) u16 Ah[128 * 64], Bh[128 * 64];
  int wid = xcd_swz(blockIdx.x, 512);
  int rb = wid & 15, cbm = wid >> 4;
  int mat = cbm >> 3;
  int col0 = (cbm & 7) * 128, row0 = rb * 128;
  const u16* Bt = Wt + (size_t)mat * C_ * K;
  const float* bias;
  if (mat == 0)      bias = bb0;
  else if (mat == 1) bias = bb1;
  else if (mat == 2) bias = bb2;
  else               bias = bb3;

  f32x4 acc[4][4];
#pragma unroll
  for (int i = 0; i < 4; i++)
#pragma unroll
    for (int j = 0; j < 4; j++) acc[i][j] = (f32x4){0.f, 0.f, 0.f, 0.f};
  gemm_core(X, Bt, K, row0, col0, Ah, Bh, acc);

  int lane = threadIdx.x & 63, w = threadIdx.x >> 6;
  int wrow = (w & 1) * 64, wcol = (w >> 1) * 64;
  if (mat < 3) {
    u16* O = (mat == 0) ? O0 : (mat == 1) ? O1 : O2;
#pragma unroll
    for (int j = 0; j < 4; j++) {
      int col = col0 + wcol + j * 16 + (lane & 15);
      float bv = bias[col];
#pragma unroll
      for (int i = 0; i < 4; i++) {
        int rowb = row0 + wrow + i * 16 + (lane >> 4) * 4;
#pragma unroll
        for (int r = 0; r < 4; r++)
          O[(size_t)(rowb + r) * C_ + col] = bf16_rn(acc[i][j][r] + bv);
      }
    }
  } else {
#pragma unroll
    for (int j = 0; j < 4; j++) {
      int col = col0 + wcol + j * 16 + (lane & 15);
      float bv = bias[col];
#pragma unroll
      for (int i = 0; i < 4; i++) {
        int rowb = row0 + wrow + i * 16 + (lane >> 4) * 4;
#pragma unroll
        for (int r = 0; r < 4; r++)
          O3[(size_t)(rowb + r) * C_ + col] = acc[i][j][r] + bv;
      }
    }
  }
}

// -------------------------------------- edge embedding @ We, rank-3 form
__global__ void k_combo2(const float* __restrict__ Wr1, const float* __restrict__ br1,
                         const float* __restrict__ Wm1, const float* __restrict__ bm1,
                         const float* __restrict__ e1W,
                         const float* __restrict__ Wr2, const float* __restrict__ br2,
                         const float* __restrict__ Wm2, const float* __restrict__ bm2,
                         const float* __restrict__ e2W,
                         float* __restrict__ e1c, float* __restrict__ e2c) {
  int x = blockIdx.x;
  int conv = x >> 6;
  int jb = x & 3, kb = (x >> 2) & 15;
  const float *Wr, *br, *Wm, *bm, *eW; float* out;
  if (conv == 0) { Wr = Wr1; br = br1; Wm = Wm1; bm = bm1; eW = e1W; out = e1c; }
  else           { Wr = Wr2; br = br2; Wm = Wm2; bm = bm2; eW = e2W; out = e2c; }
  int tid = threadIdx.x;
  __shared__ float sw[3][64];
  int k0 = kb * 64;
  if (tid < 64) {
    sw[0][tid] = Wr[k0 + tid];
    sw[1][tid] = Wm[k0 + tid];
    sw[2][tid] = br[k0 + tid] + bm[k0 + tid];
  }
  __syncthreads();
  int j = jb * 256 + tid;
  float a0 = 0.f, a1 = 0.f, a2 = 0.f;
#pragma unroll 8
  for (int kk = 0; kk < 64; kk++) {
    float w = eW[(size_t)(k0 + kk) * C_ + j];
    a0 += sw[0][kk] * w; a1 += sw[1][kk] * w; a2 += sw[2][kk] * w;
  }
#pragma unroll
  for (int c = 0; c < 10; c++)
    atomicAdd(&out[c * C_ + j], (float)(c >> 1) * a0 + (float)(c & 1) * a1 + a2);
}

// ------------------------------------------------- CSR build
__global__ void k_count(const int* __restrict__ dst, int* __restrict__ cnt) {
  int eg = blockIdx.x * 256 + threadIdx.x;
  atomicAdd(&cnt[dst[eg]], 1);
}

__global__ void k_scan(const int* __restrict__ cnt, int* __restrict__ off) {
  __shared__ int part[256];
  int t = threadIdx.x;
  int local[8]; int s = 0;
#pragma unroll
  for (int i = 0; i < 8; i++) { local[i] = cnt[t * 8 + i]; s += local[i]; }
  part[t] = s;
  __syncthreads();
  if (t == 0) {
    int r = 0;
    for (int i = 0; i < 256; i++) { int v = part[i]; part[i] = r; r += v; }
    off[N_] = r;
  }
  __syncthreads();
  int r = part[t];
#pragma unroll
  for (int i = 0; i < 8; i++) { off[t * 8 + i] = r; r += local[i]; }
}

__global__ void k_scatter(const int* __restrict__ dst, int* __restrict__ wcnt,
                          const int* __restrict__ off, int* __restrict__ perm) {
  int eg = blockIdx.x * 256 + threadIdx.x;
  int d = dst[eg];
  int p = atomicAdd(&wcnt[d], 1);
  perm[off[d] + p] = eg;
}

// ------------------------------------------------- per-dst attention agg (bf16 q/k/v)
__global__ void k_agg(const u16* __restrict__ q, const u16* __restrict__ k,
                      const u16* __restrict__ v, const float* __restrict__ ec,
                      const int* __restrict__ srcA, const float* __restrict__ etype,
                      const float* __restrict__ emain, const int* __restrict__ off,
                      const int* __restrict__ perm, float* __restrict__ O) {
  int dst = blockIdx.x;
  int beg = off[dst];
  int cntE = off[dst + 1] - beg;
  if (cntE == 0) return;
  if (cntE > 128) cntE = 128;
  int tid = threadIdx.x;
  __shared__ float lg[128][8];
  __shared__ int srcs[128];
  __shared__ int cids[128];
  for (int e = tid; e < cntE; e += 256) {
    int eg = perm[beg + e];
    srcs[e] = srcA[eg];
    cids[e] = ((int)(etype[eg] + 0.5f)) * 2 + (int)(emain[eg] + 0.5f);
  }
  __syncthreads();
  int c = tid * 4;
  int h = tid >> 5;
  ushort4 q4 = *(const ushort4*)&q[(size_t)dst * C_ + c];
  float qx = bf2f(q4.x), qy = bf2f(q4.y), qz = bf2f(q4.z), qw = bf2f(q4.w);
  const float scale = 0.08838834764831845f;  // 1/sqrt(128)
  for (int e = 0; e < cntE; e++) {
    int s = srcs[e], ci = cids[e];
    ushort4 k4 = *(const ushort4*)&k[(size_t)s * C_ + c];
    float4 ev = *(const float4*)&ec[ci * C_ + c];
    float p = qx * (bf2f(k4.x) + ev.x) + qy * (bf2f(k4.y) + ev.y) +
              qz * (bf2f(k4.z) + ev.z) + qw * (bf2f(k4.w) + ev.w);
#pragma unroll
    for (int o = 16; o; o >>= 1) p += __shfl_xor(p, o);
    if ((tid & 31) == 0) lg[e][h] = p * scale;
  }
  __syncthreads();
  if (tid < 8) {
    float m = -1e30f;
    for (int e = 0; e < cntE; e++) m = fmaxf(m, lg[e][tid]);
    float ssum = 0.f;
    for (int e = 0; e < cntE; e++) { float x = expf(lg[e][tid] - m); lg[e][tid] = x; ssum += x; }
    float inv = 1.f / ssum;
    for (int e = 0; e < cntE; e++) lg[e][tid] *= inv;
  }
  __syncthreads();
  float4 acc = {0.f, 0.f, 0.f, 0.f};
  for (int e = 0; e < cntE; e++) {
    float a = lg[e][h];
    int s = srcs[e], ci = cids[e];
    ushort4 v4 = *(const ushort4*)&v[(size_t)s * C_ + c];
    float4 ev = *(const float4*)&ec[ci * C_ + c];
    acc.x += a * (bf2f(v4.x) + ev.x); acc.y += a * (bf2f(v4.y) + ev.y);
    acc.z += a * (bf2f(v4.z) + ev.z); acc.w += a * (bf2f(v4.w) + ev.w);
  }
  float4 o = *(const float4*)&O[(size_t)dst * C_ + c];
  o.x += acc.x; o.y += acc.y; o.z += acc.z; o.w += acc.w;
  *(float4*)&O[(size_t)dst * C_ + c] = o;
}

// ------------------------------------------------- final gather + FC
__global__ void k_final(const float* __restrict__ nB, const int* __restrict__ lens,
                        const float* __restrict__ fcW, const float* __restrict__ fcb,
                        float* __restrict__ out) {
  int b = blockIdx.x;
  int idx = lens[b] - 1;
  const float* row = &nB[(b * E_ + idx) * C_];
  int tid = threadIdx.x;
  int c = tid * 4;
  float4 r = *(const float4*)&row[c];
  float4 w0 = *(const float4*)&fcW[(c + 0) * 4];
  float4 w1 = *(const float4*)&fcW[(c + 1) * 4];
  float4 w2 = *(const float4*)&fcW[(c + 2) * 4];
  float4 w3 = *(const float4*)&fcW[(c + 3) * 4];
  float p0 = r.x * w0.x + r.y * w1.x + r.z * w2.x + r.w * w3.x;
  float p1 = r.x * w0.y + r.y * w1.y + r.z * w2.y + r.w * w3.y;
  float p2 = r.x * w0.z + r.y * w1.z + r.z * w2.z + r.w * w3.z;
  float p3 = r.x * w0.w + r.y * w1.w + r.z * w2.w + r.w * w3.w;
#pragma unroll
  for (int o = 32; o; o >>= 1) {
    p0 += __shfl_xor(p0, o); p1 += __shfl_xor(p1, o);
    p2 += __shfl_xor(p2, o); p3 += __shfl_xor(p3, o);
  }
  __shared__ float red[4][4];
  if ((tid & 63) == 0) {
    int w = tid >> 6;
    red[w][0] = p0; red[w][1] = p1; red[w][2] = p2; red[w][3] = p3;
  }
  __syncthreads();
  if (tid == 0) {
#pragma unroll
    for (int j = 0; j < 4; j++)
      out[b * 4 + j] = red[0][j] + red[1][j] + red[2][j] + red[3][j] + fcb[j];
  }
}

// ================================================================ launch
extern "C" void kernel_launch(void* const* d_in, const int* in_sizes, int n_in,
                              void* d_out, int out_size, void* d_ws, size_t ws_size,
                              hipStream_t stream) {
  (void)in_sizes; (void)n_in; (void)out_size; (void)ws_size;
  const float* lh    = (const float*)d_in[0];
  const float* mask  = (const float*)d_in[1];
  const int*   lens  = (const int*)d_in[2];
  const int*   edge  = (const int*)d_in[3];
  const float* etype = (const float*)d_in[4];
  const float* emain = (const float*)d_in[5];
  const float* W1   = (const float*)d_in[6];
  const float* b1   = (const float*)d_in[7];
  const float* W2   = (const float*)d_in[8];
  const float* b2   = (const float*)d_in[9];
  const float* Wr1  = (const float*)d_in[10];
  const float* br1  = (const float*)d_in[11];
  const float* Wm1  = (const float*)d_in[12];
  const float* bm1  = (const float*)d_in[13];
  const float* Wr2  = (const float*)d_in[14];
  const float* br2  = (const float*)d_in[15];
  const float* Wm2  = (const float*)d_in[16];
  const float* bm2  = (const float*)d_in[17];
  const float* q1W  = (const float*)d_in[18];
  const float* q1b  = (const float*)d_in[19];
  const float* k1W  = (const float*)d_in[20];
  const float* k1b  = (const float*)d_in[21];
  const float* v1W  = (const float*)d_in[22];
  const float* v1b  = (const float*)d_in[23];
  const float* e1W  = (const float*)d_in[24];
  const float* s1W  = (const float*)d_in[25];
  const float* s1b  = (const float*)d_in[26];
  const float* q2W  = (const float*)d_in[27];
  const float* q2b  = (const float*)d_in[28];
  const float* k2W  = (const float*)d_in[29];
  const float* k2b  = (const float*)d_in[30];
  const float* v2W  = (const float*)d_in[31];
  const float* v2b  = (const float*)d_in[32];
  const float* e2W  = (const float*)d_in[33];
  const float* s2W  = (const float*)d_in[34];
  const float* s2b  = (const float*)d_in[35];
  const float* fcW  = (const float*)d_in[36];
  const float* fcb  = (const float*)d_in[37];

  float* ws    = (float*)d_ws;
  float* node0 = ws + 32768;               // 2048*768 fp32
  float* e1c   = node0 + ND_;              // 10*1024
  float* e2c   = e1c + 10 * 1024;
  u16* qb16 = (u16*)(e2c + 10 * 1024);     // 2048*1024 u16 each
  u16* kb16 = qb16 + (size_t)N_ * C_;
  u16* vb16 = kb16 + (size_t)N_ * C_;
  float* nA   = (float*)(vb16 + (size_t)N_ * C_);  // 2048*1024 fp32
  float* nBuf = nA + (size_t)N_ * C_;
  int* cnt  = (int*)(nBuf + (size_t)N_ * C_);  // 2048
  int* wcnt = cnt + N_;                    // 2048
  int* off  = wcnt + N_;                   // 2049 (pad to 2056)
  int* perm = off + (N_ + 8);              // 32768
  u16* wtb  = (u16*)(perm + EG_);          // all 9 bf16 transposed weights
  u16* w1t  = wtb;                         // 512*768
  u16* wt1  = w1t + SH_ * D_;              // 4*1024*768
  u16* wt2  = wt1 + 4 * (size_t)C_ * D_;   // 4*1024*1024

  // transient aliases (consumed before conv1 gemm4 overwrites them)
  u16*   pr16 = qb16;                      // probs bf16: 2048*512 u16 = 2 MB
  float* att4 = (float*)kb16;              // span partials: 4*32768 fp32 = 512 KB

  const int* srcA = edge;
  const int* dstA = edge + EG_;

  // CSR build (shared by both convs)
  (void)hipMemsetAsync(cnt, 0, 2 * N_ * sizeof(int), stream);
  k_count<<<EG_ / 256, 256, 0, stream>>>(dstA, cnt);
  k_scan<<<1, 256, 0, stream>>>(cnt, off);
  k_scatter<<<EG_ / 256, 256, 0, stream>>>(dstA, wcnt, off, perm);

  // weight prep: all 9 transposes in one launch
  k_wt9<<<384 + 4 * 768 + 4 * 1024, 256, 0, stream>>>(
      W1, q1W, k1W, v1W, s1W, q2W, k2W, v2W, s2W, wtb);

  // span attention -> att4 partials (128x128 tiles, 4 blocks/CU, XCD-swizzled)
  k_span_m<<<1024, 512, 0, stream>>>(lh, w1t, b1, W2, att4);

  // 10-combo edge embeddings (rank-3 decomposition)
  (void)hipMemsetAsync(e1c, 0, 20 * C_ * sizeof(float), stream);
  k_combo2<<<128, 256, 0, stream>>>(Wr1, br1, Wm1, bm1, e1W,
                                    Wr2, br2, Wm2, bm2, e2W, e1c, e2c);

  // pooling: probs (bf16) -> MFMA pool
  k_probs<<<256, 256, 0, stream>>>(att4, b2, mask, pr16);
  k_pool_m<<<384, 256, 0, stream>>>(lh, pr16, node0);

  // conv1
  k_gemm4_m<<<512, 256, 0, stream>>>(node0, D_, wt1,
                                     q1b, k1b, v1b, s1b, qb16, kb16, vb16, nA);
  k_agg<<<N_, 256, 0, stream>>>(qb16, kb16, vb16, e1c, srcA, etype, emain, off, perm, nA);

  // conv2
  k_gemm4_m<<<512, 256, 0, stream>>>(nA, C_, wt2,
                                     q2b, k2b, v2b, s2b, qb16, kb16, vb16, nBuf);
  k_agg<<<N_, 256, 0, stream>>>(qb16, kb16, vb16, e2c, srcA, etype, emain, off, perm, nBuf);

  // final
  k_final<<<B_, 256, 0, stream>>>(nBuf, lens, fcW, fcb, (float*)d_out);
}

// Round 17
// 219.384 us; speedup vs baseline: 1.0633x; 1.0633x over previous
//
#include <hip/hip_runtime.h>
#include <math.h>
#include <stdint.h>

#define B_  64
#define E_  32
#define L_  512
#define D_  768
#define C_  1024
#define H_  8
#define EG_ 32768
#define SH_ 512
#define N_  2048   // B*E
#define ND_ (N_ * D_)

typedef __bf16 bf16x8 __attribute__((ext_vector_type(8)));
typedef float f32x4 __attribute__((ext_vector_type(4)));
typedef unsigned short u16;
typedef u16 u16x4 __attribute__((ext_vector_type(4)));

// ---------------------------------------------------------------- helpers

__device__ __forceinline__ u16 bf16_rn(float x) {
  unsigned u = __builtin_bit_cast(unsigned, x);
  unsigned r = u + 0x7FFFu + ((u >> 16) & 1u);
  return (u16)(r >> 16);
}

__device__ __forceinline__ float bf2f(u16 u) {
  return __builtin_bit_cast(float, (unsigned)u << 16);
}

__device__ __forceinline__ void gload16(const void* g, void* l) {
  __builtin_amdgcn_global_load_lds(
      (const __attribute__((address_space(1))) void*)(unsigned long long)(uintptr_t)g,
      (__attribute__((address_space(3))) void*)(unsigned int)(uintptr_t)l,
      16, 0, 0);
}

// XCD-aware chunked swizzle (grid must be divisible by 8)
__device__ __forceinline__ int xcd_swz(int bid, int grid) {
  return (bid & 7) * (grid >> 3) + (bid >> 3);
}

// ------------------------------------------------- merged weight prep (9 mats)
__global__ void k_wt9(const float* __restrict__ s0, const float* __restrict__ s1,
                      const float* __restrict__ s2, const float* __restrict__ s3,
                      const float* __restrict__ s4, const float* __restrict__ s5,
                      const float* __restrict__ s6, const float* __restrict__ s7,
                      const float* __restrict__ s8, u16* __restrict__ dstBase) {
  int x = blockIdx.x;
  const float* W; u16* TH; int K, Nc;
  if (x < 384) {                       // W1: 768x512
    W = s0; TH = dstBase; K = D_; Nc = SH_;
  } else if (x < 384 + 4 * 768) {      // conv1 q/k/v/s: 768x1024
    int i = (x - 384) / 768; x = (x - 384) % 768;
    W = (i == 0) ? s1 : (i == 1) ? s2 : (i == 2) ? s3 : s4;
    TH = dstBase + SH_ * D_ + (size_t)i * C_ * D_; K = D_; Nc = C_;
  } else {                             // conv2 q/k/v/s: 1024x1024
    int i = (x - 3456) / 1024; x = (x - 3456) % 1024;
    W = (i == 0) ? s5 : (i == 1) ? s6 : (i == 2) ? s7 : s8;
    TH = dstBase + SH_ * D_ + 4 * (size_t)C_ * D_ + (size_t)i * C_ * C_; K = C_; Nc = C_;
  }
  __shared__ float Ts[32][33];
  int nbk = K >> 5;
  int bk = x % nbk, bn = x / nbk;
  int tid = threadIdx.x;
  int tx = tid & 31, ty = tid >> 5;
  for (int r = ty; r < 32; r += 8)
    Ts[r][tx] = W[(size_t)(bk * 32 + r) * Nc + bn * 32 + tx];
  __syncthreads();
  for (int r = ty; r < 32; r += 8) {
    float v = Ts[tx][r];
    TH[(size_t)(bn * 32 + r) * K + bk * 32 + tx] = bf16_rn(v);
  }
}

// ------------------------------------------------- MFMA GEMM core, BK=64
// (used by k_gemm4_m) 128x128 tile, 4 waves.
__device__ __forceinline__ void gemm_core(
    const float* __restrict__ X, const u16* __restrict__ Bt,
    int K, int row0, int col0,
    u16* Ah, u16* Bh, f32x4 acc[4][4])
{
  int tid = threadIdx.x;
  int lane = tid & 63, w = tid >> 6;

  int aoff[4], boff[4];
#pragma unroll
  for (int i = 0; i < 4; i++) {
    int kc = lane >> 4;
    int rT = (w & 1) * 64 + i * 16 + (lane & 15);
    aoff[i] = rT * 128 + (((kc ^ (rT & 7)) & 7) << 4);
    int cT = (w >> 1) * 64 + i * 16 + (lane & 15);
    boff[i] = cT * 128 + (((kc ^ (cT & 7)) & 7) << 4);
  }

  int nkt = K >> 6;
  for (int kt = 0; kt < nkt; kt++) {
    int k0 = kt << 6;
    if (kt) __syncthreads();
#pragma unroll
    for (int p = 0; p < 8; p++) {
      int idx = tid + p * 256;           // 0..2047
      int r = idx >> 4, c4 = idx & 15;
      float4 v = *(const float4*)&X[(size_t)(row0 + r) * K + k0 + c4 * 4];
      u16x4 hv = {bf16_rn(v.x), bf16_rn(v.y), bf16_rn(v.z), bf16_rn(v.w)};
      int off = r * 128 + ((((c4 >> 1) ^ (r & 7)) & 7) << 4) + (c4 & 1) * 8;
      *(u16x4*)((char*)Ah + off) = hv;
    }
#pragma unroll
    for (int q = 0; q < 4; q++) {
      int rT = w * 32 + q * 8 + (lane >> 3);
      int cs = (lane & 7) ^ (rT & 7);
      size_t gb = (size_t)(col0 + rT) * K + k0 + cs * 8;
      int lb = (w * 32 + q * 8) * 64;
      gload16(&Bt[gb], &Bh[lb]);
    }
    __syncthreads();
    bf16x8 ah0[4], ah1[4];
#pragma unroll
    for (int i = 0; i < 4; i++) {
      ah0[i] = *(const bf16x8*)((const char*)Ah + aoff[i]);
      ah1[i] = *(const bf16x8*)((const char*)Ah + (aoff[i] ^ 64));
    }
#pragma unroll
    for (int j = 0; j < 4; j++) {
      bf16x8 bh0 = *(const bf16x8*)((const char*)Bh + boff[j]);
#pragma unroll
      for (int i = 0; i < 4; i++)
        acc[i][j] = __builtin_amdgcn_mfma_f32_16x16x32_bf16(ah0[i], bh0, acc[i][j], 0, 0, 0);
      bf16x8 bh1 = *(const bf16x8*)((const char*)Bh + (boff[j] ^ 64));
#pragma unroll
      for (int i = 0; i < 4; i++)
        acc[i][j] = __builtin_amdgcn_mfma_f32_16x16x32_bf16(ah1[i], bh1, acc[i][j], 0, 0, 0);
    }
  }
}

// ------------------------------------------------- span MLP: 128x256 tile/block
// grid 512 = rb(256) x cb(2), XCD-chunk-swizzled so cb-pairs share an XCD L2.
// 512 threads, 8 waves (rh=w&1 x cq=w>>1); 2 blocks/CU.
__global__ __launch_bounds__(512, 4) void k_span_m(
    const float* __restrict__ lh, const u16* __restrict__ W1t,
    const float* __restrict__ b1, const float* __restrict__ W2,
    float* __restrict__ att2) {
  __shared__ __align__(16) u16 Ah[128 * 64];   // 16 KB
  __shared__ __align__(16) u16 Bh[256 * 64];   // 32 KB
  int wid = xcd_swz(blockIdx.x, 512);
  int rb = wid >> 1, cb = wid & 1;
  int row0 = rb * 128, col0 = cb * 256;
  int tid = threadIdx.x, lane = tid & 63, w = tid >> 6;
  int rh = w & 1, cq = w >> 1;

  f32x4 acc[4][4];
#pragma unroll
  for (int i = 0; i < 4; i++)
#pragma unroll
    for (int j = 0; j < 4; j++) acc[i][j] = (f32x4){0.f, 0.f, 0.f, 0.f};

  int kc = lane >> 4;
  int aoff[4], boff[4];
#pragma unroll
  for (int i = 0; i < 4; i++) {
    int rT = rh * 64 + i * 16 + (lane & 15);
    aoff[i] = rT * 128 + (((kc ^ (rT & 7)) & 7) << 4);
  }
#pragma unroll
  for (int j = 0; j < 4; j++) {
    int cT = cq * 64 + j * 16 + (lane & 15);
    boff[j] = cT * 128 + (((kc ^ (cT & 7)) & 7) << 4);
  }

  for (int kt = 0; kt < 12; kt++) {     // K = 768, BK = 64
    int k0 = kt << 6;
    if (kt) __syncthreads();
    // A: 128 rows x 64k from lh; 4 float4 / thread
#pragma unroll
    for (int p = 0; p < 4; p++) {
      int idx = tid + p * 512;           // 0..2047
      int r = idx >> 4, c4 = idx & 15;
      float4 v = *(const float4*)&lh[(size_t)(row0 + r) * D_ + k0 + c4 * 4];
      u16x4 hv = {bf16_rn(v.x), bf16_rn(v.y), bf16_rn(v.z), bf16_rn(v.w)};
      int off = r * 128 + ((((c4 >> 1) ^ (r & 7)) & 7) << 4) + (c4 & 1) * 8;
      *(u16x4*)((char*)Ah + off) = hv;
    }
    // B: 256 W1t rows x 64k via global_load_lds (inverse-swizzled source)
#pragma unroll
    for (int q = 0; q < 4; q++) {
      int rT = w * 32 + q * 8 + (lane >> 3);   // 0..255
      int cs = (lane & 7) ^ (rT & 7);
      size_t gb = (size_t)(col0 + rT) * D_ + k0 + cs * 8;
      int lb = (w * 32 + q * 8) * 64;          // u16 units, wave-uniform
      gload16(&W1t[gb], &Bh[lb]);
    }
    __syncthreads();
    bf16x8 ah0[4], ah1[4];
#pragma unroll
    for (int i = 0; i < 4; i++) {
      ah0[i] = *(const bf16x8*)((const char*)Ah + aoff[i]);
      ah1[i] = *(const bf16x8*)((const char*)Ah + (aoff[i] ^ 64));
    }
#pragma unroll
    for (int j = 0; j < 4; j++) {
      bf16x8 bh0 = *(const bf16x8*)((const char*)Bh + boff[j]);
#pragma unroll
      for (int i = 0; i < 4; i++)
        acc[i][j] = __builtin_amdgcn_mfma_f32_16x16x32_bf16(ah0[i], bh0, acc[i][j], 0, 0, 0);
      bf16x8 bh1 = *(const bf16x8*)((const char*)Bh + (boff[j] ^ 64));
#pragma unroll
      for (int i = 0; i < 4; i++)
        acc[i][j] = __builtin_amdgcn_mfma_f32_16x16x32_bf16(ah1[i], bh1, acc[i][j], 0, 0, 0);
    }
  }

  // epilogue: per-row partial over this block's 256 cols -> att2[cb]
  float b1v[4], w2v[4];
#pragma unroll
  for (int j = 0; j < 4; j++) {
    int col = col0 + cq * 64 + j * 16 + (lane & 15);
    b1v[j] = b1[col]; w2v[j] = W2[col];
  }
  __syncthreads();                       // done with Ah; reuse as reduce buffer
  float* sred = (float*)Ah;              // [4][128] = 2 KB
#pragma unroll
  for (int i = 0; i < 4; i++) {
#pragma unroll
    for (int r = 0; r < 4; r++) {
      float s = 0.f;
#pragma unroll
      for (int j = 0; j < 4; j++) {
        float h = acc[i][j][r] + b1v[j];
        s += fmaxf(h, 0.f) * w2v[j];
      }
      s += __shfl_xor(s, 1); s += __shfl_xor(s, 2);
      s += __shfl_xor(s, 4); s += __shfl_xor(s, 8);
      if ((lane & 15) == 0)
        sred[cq * 128 + rh * 64 + i * 16 + (lane >> 4) * 4 + r] = s;
    }
  }
  __syncthreads();
  if (tid < 128)
    att2[(size_t)cb * 32768 + row0 + tid] =
        sred[tid] + sred[128 + tid] + sred[256 + tid] + sred[384 + tid];
}

// ------------------------------------------------- probs: masked softmax -> bf16
__global__ void k_probs(const float* __restrict__ att2, const float* __restrict__ b2,
                        const float* __restrict__ mask, u16* __restrict__ pr) {
  int bi = blockIdx.x >> 2, eg = blockIdx.x & 3;
  int tid = threadIdx.x, lane = tid & 63, w = tid >> 6;
  __shared__ float att_s[512];
  float b2v = b2[0];
  int r0 = bi * 512 + tid;
  att_s[tid]       = att2[r0] + att2[32768 + r0] + b2v;
  att_s[tid + 256] = att2[r0 + 256] + att2[32768 + r0 + 256] + b2v;
  __syncthreads();
#pragma unroll
  for (int it = 0; it < 2; it++) {
    int e = eg * 8 + it * 4 + w;
    const float* mrow = &mask[(size_t)(bi * E_ + e) * L_];
    float4 m0 = *(const float4*)&mrow[lane * 8];
    float4 m1 = *(const float4*)&mrow[lane * 8 + 4];
    float4 a0 = *(const float4*)&att_s[lane * 8];
    float4 a1 = *(const float4*)&att_s[lane * 8 + 4];
    float v[8];
    v[0] = a0.x - 1e5f * (1.f - m0.x); v[1] = a0.y - 1e5f * (1.f - m0.y);
    v[2] = a0.z - 1e5f * (1.f - m0.z); v[3] = a0.w - 1e5f * (1.f - m0.w);
    v[4] = a1.x - 1e5f * (1.f - m1.x); v[5] = a1.y - 1e5f * (1.f - m1.y);
    v[6] = a1.z - 1e5f * (1.f - m1.z); v[7] = a1.w - 1e5f * (1.f - m1.w);
    float mx = v[0];
#pragma unroll
    for (int i = 1; i < 8; i++) mx = fmaxf(mx, v[i]);
#pragma unroll
    for (int o = 32; o; o >>= 1) mx = fmaxf(mx, __shfl_xor(mx, o));
    float s = 0.f;
#pragma unroll
    for (int i = 0; i < 8; i++) { v[i] = expf(v[i] - mx); s += v[i]; }
#pragma unroll
    for (int o = 32; o; o >>= 1) s += __shfl_xor(s, o);
    float inv = 1.f / s;
    u16x4 o0 = {bf16_rn(v[0] * inv), bf16_rn(v[1] * inv), bf16_rn(v[2] * inv), bf16_rn(v[3] * inv)};
    u16x4 o1 = {bf16_rn(v[4] * inv), bf16_rn(v[5] * inv), bf16_rn(v[6] * inv), bf16_rn(v[7] * inv)};
    u16* prow = &pr[(size_t)(bi * E_ + e) * L_];
    *(u16x4*)&prow[lane * 8] = o0;
    *(u16x4*)&prow[lane * 8 + 4] = o1;
  }
}

// ------------------------------------------------- pool via MFMA (bf16 probs)
__global__ __launch_bounds__(256) void k_pool_m(const float* __restrict__ lh,
    const u16* __restrict__ pr, float* __restrict__ node0) {
  __shared__ __align__(16) u16 As[32 * 32];
  __shared__ __align__(16) u16 Bs[32 * 128];
  int bi = blockIdx.x / 6, dc = blockIdx.x % 6;
  int col0 = dc * 128;
  int tid = threadIdx.x, lane = tid & 63, w = tid >> 6;
  const float* lhb = lh + (size_t)bi * L_ * D_;
  const u16* prb = pr + (size_t)bi * E_ * L_;

  f32x4 acc[2][2];
#pragma unroll
  for (int m = 0; m < 2; m++)
#pragma unroll
    for (int c = 0; c < 2; c++) acc[m][c] = (f32x4){0.f, 0.f, 0.f, 0.f};

  int aoff[2];
#pragma unroll
  for (int m = 0; m < 2; m++) {
    int kc = lane >> 4;
    int e = m * 16 + (lane & 15);
    aoff[m] = e * 64 + (((kc ^ ((e >> 1) & 3)) & 3) << 4);
  }
  int se = tid >> 3, sk4 = tid & 7;
  int saoff = se * 64 + ((((sk4 >> 1) ^ ((se >> 1) & 3)) & 3) << 4) + (sk4 & 1) * 8;

  for (int kt = 0; kt < 16; kt++) {
    int l0 = kt << 5;
    if (kt) __syncthreads();
    {
      u16x4 hv = *(const u16x4*)&prb[(size_t)se * L_ + l0 + sk4 * 4];
      *(u16x4*)((char*)As + saoff) = hv;
    }
#pragma unroll
    for (int p = 0; p < 4; p++) {
      int idx = tid + p * 256;
      int k = idx >> 5, c4 = idx & 31;
      float4 v = *(const float4*)&lhb[(size_t)(l0 + k) * D_ + col0 + c4 * 4];
      u16x4 hv = {bf16_rn(v.x), bf16_rn(v.y), bf16_rn(v.z), bf16_rn(v.w)};
      *(u16x4*)&Bs[k * 128 + c4 * 4] = hv;
    }
    __syncthreads();
    bf16x8 af[2];
#pragma unroll
    for (int m = 0; m < 2; m++)
      af[m] = *(const bf16x8*)((const char*)As + aoff[m]);
#pragma unroll
    for (int c = 0; c < 2; c++) {
      int colT = w * 32 + c * 16 + (lane & 15);
      int kg = (lane >> 4) * 8;
      union { bf16x8 v; u16 u[8]; } bb;
#pragma unroll
      for (int j = 0; j < 8; j++) bb.u[j] = Bs[(kg + j) * 128 + colT];
#pragma unroll
      for (int m = 0; m < 2; m++)
        acc[m][c] = __builtin_amdgcn_mfma_f32_16x16x32_bf16(af[m], bb.v, acc[m][c], 0, 0, 0);
    }
  }
#pragma unroll
  for (int m = 0; m < 2; m++)
#pragma unroll
    for (int c = 0; c < 2; c++) {
      int col = col0 + w * 32 + c * 16 + (lane & 15);
#pragma unroll
      for (int r = 0; r < 4; r++) {
        int e = m * 16 + (lane >> 4) * 4 + r;
        node0[(size_t)(bi * E_ + e) * D_ + col] = acc[m][c][r];
      }
    }
}

// ------------------------------------------------- fused q/k/v/skip GEMM (MFMA)
// q,k,v outputs bf16; skip output fp32. XCD-chunk-swizzled.
__global__ __launch_bounds__(256) void k_gemm4_m(
    const float* __restrict__ X, int K,
    const u16* __restrict__ Wt,
    const float* __restrict__ bb0, const float* __restrict__ bb1,
    const float* __restrict__ bb2, const float* __restrict__ bb3,
    u16* __restrict__ O0, u16* __restrict__ O1,
    u16* __restrict__ O2, float* __restrict__ O3) {
  __shared__ __align__(16) u16 Ah[128 * 64], Bh[128 * 64];
  int wid = xcd_swz(blockIdx.x, 512);
  int rb = wid & 15, cbm = wid >> 4;
  int mat = cbm >> 3;
  int col0 = (cbm & 7) * 128, row0 = rb * 128;
  const u16* Bt = Wt + (size_t)mat * C_ * K;
  const float* bias;
  if (mat == 0)      bias = bb0;
  else if (mat == 1) bias = bb1;
  else if (mat == 2) bias = bb2;
  else               bias = bb3;

  f32x4 acc[4][4];
#pragma unroll
  for (int i = 0; i < 4; i++)
#pragma unroll
    for (int j = 0; j < 4; j++) acc[i][j] = (f32x4){0.f, 0.f, 0.f, 0.f};
  gemm_core(X, Bt, K, row0, col0, Ah, Bh, acc);

  int lane = threadIdx.x & 63, w = threadIdx.x >> 6;
  int wrow = (w & 1) * 64, wcol = (w >> 1) * 64;
  if (mat < 3) {
    u16* O = (mat == 0) ? O0 : (mat == 1) ? O1 : O2;
#pragma unroll
    for (int j = 0; j < 4; j++) {
      int col = col0 + wcol + j * 16 + (lane & 15);
      float bv = bias[col];
#pragma unroll
      for (int i = 0; i < 4; i++) {
        int rowb = row0 + wrow + i * 16 + (lane >> 4) * 4;
#pragma unroll
        for (int r = 0; r < 4; r++)
          O[(size_t)(rowb + r) * C_ + col] = bf16_rn(acc[i][j][r] + bv);
      }
    }
  } else {
#pragma unroll
    for (int j = 0; j < 4; j++) {
      int col = col0 + wcol + j * 16 + (lane & 15);
      float bv = bias[col];
#pragma unroll
      for (int i = 0; i < 4; i++) {
        int rowb = row0 + wrow + i * 16 + (lane >> 4) * 4;
#pragma unroll
        for (int r = 0; r < 4; r++)
          O3[(size_t)(rowb + r) * C_ + col] = acc[i][j][r] + bv;
      }
    }
  }
}

// -------------------------------------- edge embedding @ We, rank-3 form
__global__ void k_combo2(const float* __restrict__ Wr1, const float* __restrict__ br1,
                         const float* __restrict__ Wm1, const float* __restrict__ bm1,
                         const float* __restrict__ e1W,
                         const float* __restrict__ Wr2, const float* __restrict__ br2,
                         const float* __restrict__ Wm2, const float* __restrict__ bm2,
                         const float* __restrict__ e2W,
                         float* __restrict__ e1c, float* __restrict__ e2c) {
  int x = blockIdx.x;
  int conv = x >> 6;
  int jb = x & 3, kb = (x >> 2) & 15;
  const float *Wr, *br, *Wm, *bm, *eW; float* out;
  if (conv == 0) { Wr = Wr1; br = br1; Wm = Wm1; bm = bm1; eW = e1W; out = e1c; }
  else           { Wr = Wr2; br = br2; Wm = Wm2; bm = bm2; eW = e2W; out = e2c; }
  int tid = threadIdx.x;
  __shared__ float sw[3][64];
  int k0 = kb * 64;
  if (tid < 64) {
    sw[0][tid] = Wr[k0 + tid];
    sw[1][tid] = Wm[k0 + tid];
    sw[2][tid] = br[k0 + tid] + bm[k0 + tid];
  }
  __syncthreads();
  int j = jb * 256 + tid;
  float a0 = 0.f, a1 = 0.f, a2 = 0.f;
#pragma unroll 8
  for (int kk = 0; kk < 64; kk++) {
    float w = eW[(size_t)(k0 + kk) * C_ + j];
    a0 += sw[0][kk] * w; a1 += sw[1][kk] * w; a2 += sw[2][kk] * w;
  }
#pragma unroll
  for (int c = 0; c < 10; c++)
    atomicAdd(&out[c * C_ + j], (float)(c >> 1) * a0 + (float)(c & 1) * a1 + a2);
}

// ------------------------------------------------- CSR build
__global__ void k_count(const int* __restrict__ dst, int* __restrict__ cnt) {
  int eg = blockIdx.x * 256 + threadIdx.x;
  atomicAdd(&cnt[dst[eg]], 1);
}

__global__ void k_scan(const int* __restrict__ cnt, int* __restrict__ off) {
  __shared__ int part[256];
  int t = threadIdx.x;
  int local[8]; int s = 0;
#pragma unroll
  for (int i = 0; i < 8; i++) { local[i] = cnt[t * 8 + i]; s += local[i]; }
  part[t] = s;
  __syncthreads();
  if (t == 0) {
    int r = 0;
    for (int i = 0; i < 256; i++) { int v = part[i]; part[i] = r; r += v; }
    off[N_] = r;
  }
  __syncthreads();
  int r = part[t];
#pragma unroll
  for (int i = 0; i < 8; i++) { off[t * 8 + i] = r; r += local[i]; }
}

__global__ void k_scatter(const int* __restrict__ dst, int* __restrict__ wcnt,
                          const int* __restrict__ off, int* __restrict__ perm) {
  int eg = blockIdx.x * 256 + threadIdx.x;
  int d = dst[eg];
  int p = atomicAdd(&wcnt[d], 1);
  perm[off[d] + p] = eg;
}

// ------------------------------------------------- per-dst attention agg (bf16 q/k/v)
__global__ void k_agg(const u16* __restrict__ q, const u16* __restrict__ k,
                      const u16* __restrict__ v, const float* __restrict__ ec,
                      const int* __restrict__ srcA, const float* __restrict__ etype,
                      const float* __restrict__ emain, const int* __restrict__ off,
                      const int* __restrict__ perm, float* __restrict__ O) {
  int dst = blockIdx.x;
  int beg = off[dst];
  int cntE = off[dst + 1] - beg;
  if (cntE == 0) return;
  if (cntE > 128) cntE = 128;
  int tid = threadIdx.x;
  __shared__ float lg[128][8];
  __shared__ int srcs[128];
  __shared__ int cids[128];
  for (int e = tid; e < cntE; e += 256) {
    int eg = perm[beg + e];
    srcs[e] = srcA[eg];
    cids[e] = ((int)(etype[eg] + 0.5f)) * 2 + (int)(emain[eg] + 0.5f);
  }
  __syncthreads();
  int c = tid * 4;
  int h = tid >> 5;
  ushort4 q4 = *(const ushort4*)&q[(size_t)dst * C_ + c];
  float qx = bf2f(q4.x), qy = bf2f(q4.y), qz = bf2f(q4.z), qw = bf2f(q4.w);
  const float scale = 0.08838834764831845f;  // 1/sqrt(128)
  for (int e = 0; e < cntE; e++) {
    int s = srcs[e], ci = cids[e];
    ushort4 k4 = *(const ushort4*)&k[(size_t)s * C_ + c];
    float4 ev = *(const float4*)&ec[ci * C_ + c];
    float p = qx * (bf2f(k4.x) + ev.x) + qy * (bf2f(k4.y) + ev.y) +
              qz * (bf2f(k4.z) + ev.z) + qw * (bf2f(k4.w) + ev.w);
#pragma unroll
    for (int o = 16; o; o >>= 1) p += __shfl_xor(p, o);
    if ((tid & 31) == 0) lg[e][h] = p * scale;
  }
  __syncthreads();
  if (tid < 8) {
    float m = -1e30f;
    for (int e = 0; e < cntE; e++) m = fmaxf(m, lg[e][tid]);
    float ssum = 0.f;
    for (int e = 0; e < cntE; e++) { float x = expf(lg[e][tid] - m); lg[e][tid] = x; ssum += x; }
    float inv = 1.f / ssum;
    for (int e = 0; e < cntE; e++) lg[e][tid] *= inv;
  }
  __syncthreads();
  float4 acc = {0.f, 0.f, 0.f, 0.f};
  for (int e = 0; e < cntE; e++) {
    float a = lg[e][h];
    int s = srcs[e], ci = cids[e];
    ushort4 v4 = *(const ushort4*)&v[(size_t)s * C_ + c];
    float4 ev = *(const float4*)&ec[ci * C_ + c];
    acc.x += a * (bf2f(v4.x) + ev.x); acc.y += a * (bf2f(v4.y) + ev.y);
    acc.z += a * (bf2f(v4.z) + ev.z); acc.w += a * (bf2f(v4.w) + ev.w);
  }
  float4 o = *(const float4*)&O[(size_t)dst * C_ + c];
  o.x += acc.x; o.y += acc.y; o.z += acc.z; o.w += acc.w;
  *(float4*)&O[(size_t)dst * C_ + c] = o;
}

// ------------------------------------------------- final gather + FC
__global__ void k_final(const float* __restrict__ nB, const int* __restrict__ lens,
                        const float* __restrict__ fcW, const float* __restrict__ fcb,
                        float* __restrict__ out) {
  int b = blockIdx.x;
  int idx = lens[b] - 1;
  const float* row = &nB[(b * E_ + idx) * C_];
  int tid = threadIdx.x;
  int c = tid * 4;
  float4 r = *(const float4*)&row[c];
  float4 w0 = *(const float4*)&fcW[(c + 0) * 4];
  float4 w1 = *(const float4*)&fcW[(c + 1) * 4];
  float4 w2 = *(const float4*)&fcW[(c + 2) * 4];
  float4 w3 = *(const float4*)&fcW[(c + 3) * 4];
  float p0 = r.x * w0.x + r.y * w1.x + r.z * w2.x + r.w * w3.x;
  float p1 = r.x * w0.y + r.y * w1.y + r.z * w2.y + r.w * w3.y;
  float p2 = r.x * w0.z + r.y * w1.z + r.z * w2.z + r.w * w3.z;
  float p3 = r.x * w0.w + r.y * w1.w + r.z * w2.w + r.w * w3.w;
#pragma unroll
  for (int o = 32; o; o >>= 1) {
    p0 += __shfl_xor(p0, o); p1 += __shfl_xor(p1, o);
    p2 += __shfl_xor(p2, o); p3 += __shfl_xor(p3, o);
  }
  __shared__ float red[4][4];
  if ((tid & 63) == 0) {
    int w = tid >> 6;
    red[w][0] = p0; red[w][1] = p1; red[w][2] = p2; red[w][3] = p3;
  }
  __syncthreads();
  if (tid == 0) {
#pragma unroll
    for (int j = 0; j < 4; j++)
      out[b * 4 + j] = red[0][j] + red[1][j] + red[2][j] + red[3][j] + fcb[j];
  }
}

// ================================================================ launch
extern "C" void kernel_launch(void* const* d_in, const int* in_sizes, int n_in,
                              void* d_out, int out_size, void* d_ws, size_t ws_size,
                              hipStream_t stream) {
  (void)in_sizes; (void)n_in; (void)out_size; (void)ws_size;
  const float* lh    = (const float*)d_in[0];
  const float* mask  = (const float*)d_in[1];
  const int*   lens  = (const int*)d_in[2];
  const int*   edge  = (const int*)d_in[3];
  const float* etype = (const float*)d_in[4];
  const float* emain = (const float*)d_in[5];
  const float* W1   = (const float*)d_in[6];
  const float* b1   = (const float*)d_in[7];
  const float* W2   = (const float*)d_in[8];
  const float* b2   = (const float*)d_in[9];
  const float* Wr1  = (const float*)d_in[10];
  const float* br1  = (const float*)d_in[11];
  const float* Wm1  = (const float*)d_in[12];
  const float* bm1  = (const float*)d_in[13];
  const float* Wr2  = (const float*)d_in[14];
  const float* br2  = (const float*)d_in[15];
  const float* Wm2  = (const float*)d_in[16];
  const float* bm2  = (const float*)d_in[17];
  const float* q1W  = (const float*)d_in[18];
  const float* q1b  = (const float*)d_in[19];
  const float* k1W  = (const float*)d_in[20];
  const float* k1b  = (const float*)d_in[21];
  const float* v1W  = (const float*)d_in[22];
  const float* v1b  = (const float*)d_in[23];
  const float* e1W  = (const float*)d_in[24];
  const float* s1W  = (const float*)d_in[25];
  const float* s1b  = (const float*)d_in[26];
  const float* q2W  = (const float*)d_in[27];
  const float* q2b  = (const float*)d_in[28];
  const float* k2W  = (const float*)d_in[29];
  const float* k2b  = (const float*)d_in[30];
  const float* v2W  = (const float*)d_in[31];
  const float* v2b  = (const float*)d_in[32];
  const float* e2W  = (const float*)d_in[33];
  const float* s2W  = (const float*)d_in[34];
  const float* s2b  = (const float*)d_in[35];
  const float* fcW  = (const float*)d_in[36];
  const float* fcb  = (const float*)d_in[37];

  float* ws    = (float*)d_ws;
  float* node0 = ws + 32768;               // 2048*768 fp32
  float* e1c   = node0 + ND_;              // 10*1024
  float* e2c   = e1c + 10 * 1024;
  u16* qb16 = (u16*)(e2c + 10 * 1024);     // 2048*1024 u16 each
  u16* kb16 = qb16 + (size_t)N_ * C_;
  u16* vb16 = kb16 + (size_t)N_ * C_;
  float* nA   = (float*)(vb16 + (size_t)N_ * C_);  // 2048*1024 fp32
  float* nBuf = nA + (size_t)N_ * C_;
  int* cnt  = (int*)(nBuf + (size_t)N_ * C_);  // 2048
  int* wcnt = cnt + N_;                    // 2048
  int* off  = wcnt + N_;                   // 2049 (pad to 2056)
  int* perm = off + (N_ + 8);              // 32768
  u16* wtb  = (u16*)(perm + EG_);          // all 9 bf16 transposed weights
  u16* w1t  = wtb;                         // 512*768
  u16* wt1  = w1t + SH_ * D_;              // 4*1024*768
  u16* wt2  = wt1 + 4 * (size_t)C_ * D_;   // 4*1024*1024

  // transient aliases (consumed before conv1 gemm4 overwrites them)
  u16*   pr16 = qb16;                      // probs bf16: 2048*512 u16 = 2 MB
  float* att2 = (float*)kb16;              // span partials: 2*32768 fp32

  const int* srcA = edge;
  const int* dstA = edge + EG_;

  // CSR build (shared by both convs)
  (void)hipMemsetAsync(cnt, 0, 2 * N_ * sizeof(int), stream);
  k_count<<<EG_ / 256, 256, 0, stream>>>(dstA, cnt);
  k_scan<<<1, 256, 0, stream>>>(cnt, off);
  k_scatter<<<EG_ / 256, 256, 0, stream>>>(dstA, wcnt, off, perm);

  // weight prep: all 9 transposes in one launch
  k_wt9<<<384 + 4 * 768 + 4 * 1024, 256, 0, stream>>>(
      W1, q1W, k1W, v1W, s1W, q2W, k2W, v2W, s2W, wtb);

  // span attention -> att2 partials (128x256 tiles, XCD-swizzled)
  k_span_m<<<512, 512, 0, stream>>>(lh, w1t, b1, W2, att2);

  // 10-combo edge embeddings (rank-3 decomposition)
  (void)hipMemsetAsync(e1c, 0, 20 * C_ * sizeof(float), stream);
  k_combo2<<<128, 256, 0, stream>>>(Wr1, br1, Wm1, bm1, e1W,
                                    Wr2, br2, Wm2, bm2, e2W, e1c, e2c);

  // pooling: probs (bf16) -> MFMA pool
  k_probs<<<256, 256, 0, stream>>>(att2, b2, mask, pr16);
  k_pool_m<<<384, 256, 0, stream>>>(lh, pr16, node0);

  // conv1
  k_gemm4_m<<<512, 256, 0, stream>>>(node0, D_, wt1,
                                     q1b, k1b, v1b, s1b, qb16, kb16, vb16, nA);
  k_agg<<<N_, 256, 0, stream>>>(qb16, kb16, vb16, e1c, srcA, etype, emain, off, perm, nA);

  // conv2
  k_gemm4_m<<<512, 256, 0, stream>>>(nA, C_, wt2,
                                     q2b, k2b, v2b, s2b, qb16, kb16, vb16, nBuf);
  k_agg<<<N_, 256, 0, stream>>>(qb16, kb16, vb16, e2c, srcA, etype, emain, off, perm, nBuf);

  // final
  k_final<<<B_, 256, 0, stream>>>(nBuf, lens, fcW, fcb, (float*)d_out);
}